// Round 4
// baseline (299.398 us; speedup 1.0000x reference)
//
#include <hip/hip_runtime.h>

// B=32, C=256, H=64, W=64. Positions = 131072. Channel stride = 16 KiB.
// R3: kill the 2^14-byte strided access pattern (R0-R2 all plateaued at
// ~1.3 TB/s even with cache-resident data => L2/channel camping, not HBM BW).
// Pass 1 streams u,m PURELY CONTIGUOUSLY (each block: one b, 16 channels,
// all 4096 positions; 2x256KB linear), accumulating per-position partials in
// registers, writing 25 MB partials to ws. Pass 2 combines 16 chunk-partials
// per position, applies mask, double-reduces.

#define BB    32
#define CC    256
#define HWSZ  4096
#define NPOS  (BB * HWSZ)         // 131072
#define G     16                  // channels per group
#define NCG   (CC / G)            // 16 groups
#define SIM_EPS 1e-8f

// ws layout: [0..15]  two doubles (sum_sim, sum_mask)
//            [256..]  partials: float P[BB*NCG][3][HWSZ]  (25.2 MB)
#define WS_PARTIAL_OFF 256

__global__ __launch_bounds__(256) void
pass1_kernel(const float* __restrict__ u,
             const float* __restrict__ m,
             float* __restrict__ P)
{
    const int tid = threadIdx.x;
    const int b   = blockIdx.x >> 4;          // 0..31
    const int cg  = blockIdx.x & (NCG - 1);   // 0..15

    const size_t slab = ((size_t)(b * CC + cg * G)) << 12;   // *4096 floats
    const float4* up = (const float4*)(u + slab);
    const float4* mp = (const float4*)(m + slab);

    // Thread owns positions {g*1024 + tid*4 .. +3} for g=0..3 (all 4096 hw).
    float4 n[4], su[4], sm[4];
#pragma unroll
    for (int g = 0; g < 4; ++g) {
        n[g]  = make_float4(0.f, 0.f, 0.f, 0.f);
        su[g] = make_float4(0.f, 0.f, 0.f, 0.f);
        sm[g] = make_float4(0.f, 0.f, 0.f, 0.f);
    }

    for (int c = 0; c < G; ++c) {
        const size_t cbase = (size_t)c * (HWSZ / 4);   // float4 units
        float4 a[4], v[4];
#pragma unroll
        for (int g = 0; g < 4; ++g) a[g] = up[cbase + g * 256 + tid];
#pragma unroll
        for (int g = 0; g < 4; ++g) v[g] = mp[cbase + g * 256 + tid];
#pragma unroll
        for (int g = 0; g < 4; ++g) {
            n[g].x  = fmaf(a[g].x, v[g].x, n[g].x);
            n[g].y  = fmaf(a[g].y, v[g].y, n[g].y);
            n[g].z  = fmaf(a[g].z, v[g].z, n[g].z);
            n[g].w  = fmaf(a[g].w, v[g].w, n[g].w);
            su[g].x = fmaf(a[g].x, a[g].x, su[g].x);
            su[g].y = fmaf(a[g].y, a[g].y, su[g].y);
            su[g].z = fmaf(a[g].z, a[g].z, su[g].z);
            su[g].w = fmaf(a[g].w, a[g].w, su[g].w);
            sm[g].x = fmaf(v[g].x, v[g].x, sm[g].x);
            sm[g].y = fmaf(v[g].y, v[g].y, sm[g].y);
            sm[g].z = fmaf(v[g].z, v[g].z, sm[g].z);
            sm[g].w = fmaf(v[g].w, v[g].w, sm[g].w);
        }
    }

    // P[b*NCG+cg][comp][hw], comp: 0=num 1=uu 2=mm. Coalesced float4 stores.
    float4* P4 = (float4*)P;
    const size_t pb = (size_t)(blockIdx.x * 3) * (HWSZ / 4);
#pragma unroll
    for (int g = 0; g < 4; ++g) {
        P4[pb + 0 * (HWSZ / 4) + g * 256 + tid] = n[g];
        P4[pb + 1 * (HWSZ / 4) + g * 256 + tid] = su[g];
        P4[pb + 2 * (HWSZ / 4) + g * 256 + tid] = sm[g];
    }
}

__global__ __launch_bounds__(256) void
pass2_kernel(const float* __restrict__ P,
             const int* __restrict__ mask,
             double* __restrict__ ws)
{
    const int tid = threadIdx.x;
    const int p   = blockIdx.x * 256 + tid;    // 512 blocks cover NPOS
    const int b   = p >> 12;
    const int hw  = p & (HWSZ - 1);

    float n = 0.f, su = 0.f, sm = 0.f;
#pragma unroll
    for (int cg = 0; cg < NCG; ++cg) {
        const size_t base = ((size_t)(b * NCG + cg) * 3) << 12;
        n  += P[base + hw];                    // coalesced across tid
        su += P[base + HWSZ + hw];
        sm += P[base + 2 * HWSZ + hw];
    }

    const float denom = fmaxf(sqrtf(su), SIM_EPS) * fmaxf(sqrtf(sm), SIM_EPS);
    const float sim   = n / denom;
    const int   mk    = (mask[p] != 0) ? 1 : 0;
    double sd = mk ? (double)sim : 0.0;
    double md = (double)mk;

#pragma unroll
    for (int off = 32; off > 0; off >>= 1) {
        sd += __shfl_down(sd, off, 64);
        md += __shfl_down(md, off, 64);
    }

    __shared__ double red_s[4];
    __shared__ double red_m[4];
    const int wave = tid >> 6;
    const int lane = tid & 63;
    if (lane == 0) { red_s[wave] = sd; red_m[wave] = md; }
    __syncthreads();

    if (tid == 0) {
        atomicAdd(&ws[0], red_s[0] + red_s[1] + red_s[2] + red_s[3]);
        atomicAdd(&ws[1], red_m[0] + red_m[1] + red_m[2] + red_m[3]);
    }
}

__global__ void finalize_kernel(const double* __restrict__ ws,
                                float* __restrict__ out)
{
    out[0] = (float)(ws[0] / ws[1]);
}

extern "C" void kernel_launch(void* const* d_in, const int* in_sizes, int n_in,
                              void* d_out, int out_size, void* d_ws, size_t ws_size,
                              hipStream_t stream)
{
    const float* u    = (const float*)d_in[0];
    const float* m    = (const float*)d_in[1];
    const int*   mask = (const int*)d_in[2];
    float*  out = (float*)d_out;
    double* ws  = (double*)d_ws;
    float*  P   = (float*)((char*)d_ws + WS_PARTIAL_OFF);

    hipMemsetAsync(d_ws, 0, 2 * sizeof(double), stream);

    pass1_kernel<<<BB * NCG, 256, 0, stream>>>(u, m, P);
    pass2_kernel<<<NPOS / 256, 256, 0, stream>>>(P, mask, ws);
    finalize_kernel<<<1, 1, 0, stream>>>(ws, out);
}